// Round 8
// baseline (1183.866 us; speedup 1.0000x reference)
//
#include <hip/hip_runtime.h>
#include <hip/hip_bf16.h>

#define LOG2E 1.44269504088896340736f

typedef __attribute__((ext_vector_type(8))) short short8;
typedef __attribute__((ext_vector_type(2))) float f32x2;
typedef __attribute__((ext_vector_type(4))) float f32x4;
typedef __attribute__((ext_vector_type(16))) float f32x16;

__device__ __forceinline__ unsigned short f2bf(float f) {
    unsigned int u = __float_as_uint(f);
    u += 0x7fffu + ((u >> 16) & 1u);
    return (unsigned short)(u >> 16);
}

__device__ __forceinline__ unsigned cvt_pk_bf16(float a, float b) {
    unsigned r;
    asm("v_cvt_pk_bf16_f32 %0, %1, %2" : "=v"(r) : "v"(a), "v"(b));
    return r;   // low16 = bf16(a), high16 = bf16(b)
}

__device__ __forceinline__ float fast_exp2(float x) {
    float r;
    asm("v_exp_f32 %0, %1" : "=v"(r) : "v"(x));
    return r;
}

// async global(16B/lane) -> LDS (wave-uniform base + lane*16)
__device__ __forceinline__ void gl_lds16(const unsigned short* g, unsigned short* l) {
    __builtin_amdgcn_global_load_lds(
        (const __attribute__((address_space(1))) unsigned int*)g,
        (__attribute__((address_space(3))) unsigned int*)l, 16, 0, 0);
}

// ---------------- fp32 -> bf16 conversion, XOR-swizzled (ncols = 768) -------
// within each 64-col tile: 8-u16 slot' = slot ^ (row&7)
__global__ void cvt_swz(const float* __restrict__ in,
                        unsigned short* __restrict__ out, int n8) {
    int stride = gridDim.x * blockDim.x;
    for (int i = blockIdx.x * blockDim.x + threadIdx.x; i < n8; i += stride) {
        int flat = i * 8;
        int row = flat / 768;
        int col = flat - row * 768;
        float4 v0 = ((const float4*)(in + flat))[0];
        float4 v1 = ((const float4*)(in + flat))[1];
        union { unsigned short u[8]; short8 v; } o;
        o.u[0] = f2bf(v0.x); o.u[1] = f2bf(v0.y);
        o.u[2] = f2bf(v0.z); o.u[3] = f2bf(v0.w);
        o.u[4] = f2bf(v1.x); o.u[5] = f2bf(v1.y);
        o.u[6] = f2bf(v1.z); o.u[7] = f2bf(v1.w);
        int c = (col & 63) ^ ((row & 7) << 3);
        *(short8*)(out + (size_t)row * 768 + (col & ~63) + c) = o.v;
    }
}

// ---------------- GEMM: C[m][n] = sum_k A[m][k]*B[n][k] (+bias) ----------------
// A,B pre-swizzled in HBM; LDS linear dbuf via global_load_lds; 1 barrier/iter.
// BN: 128 (4 B-frags/wave) or 64 (2 B-frags, better grid balance for small N).
// EPI==0: scatter to qkv_sep; Q pre-scaled; K (N,hd) and V^T (hd,N) PLAIN.
// EPI==1: fp32 out (M x N).
template <int EPI, int BN>
__global__ __launch_bounds__(256, BN == 64 ? 3 : 2)
void gemm_bt(const unsigned short* __restrict__ A,
             const unsigned short* __restrict__ B,
             const float* __restrict__ bias,
             void* __restrict__ Cout,
             int M, int N, int K) {
    __shared__ unsigned short As[2][8192];      // [128][64] linear per buf
    __shared__ unsigned short Bs[2][BN * 64];
    constexpr int NB = BN / 32;                 // B frags per wave; B stage iters

    const int tid  = threadIdx.x;
    const int wave = tid >> 6, lane = tid & 63;
    const int fr = lane & 15, fg = lane >> 4;
    const int wm = (wave >> 1) * 64, wn = (wave & 1) * (BN / 2);
    const int m0 = blockIdx.y * 128, n0 = blockIdx.x * BN;
    const int sr = lane >> 3, ss = lane & 7;

    f32x4 acc[4][NB];
#pragma unroll
    for (int m = 0; m < 4; m++)
#pragma unroll
        for (int n = 0; n < NB; n++) acc[m][n] = (f32x4){0.f, 0.f, 0.f, 0.f};

    const int NT = K >> 6;

    // each gl_lds16 call: 4 waves x 8 rows = 32 rows -> A needs 4 iters,
    // B needs NB iters (BN/32).
#define GEMM_STAGE(buf, k0)                                                     \
    {                                                                           \
        _Pragma("unroll")                                                       \
        for (int c = 0; c < 4; c++) {                                           \
            int rr = (c * 4 + wave) * 8 + sr;                                   \
            gl_lds16(A + (size_t)(m0 + rr) * K + (k0) + ss * 8,                 \
                     &As[buf][(c * 4 + wave) * 512]);                           \
        }                                                                       \
        _Pragma("unroll")                                                       \
        for (int c = 0; c < NB; c++) {                                          \
            int rr = (c * 4 + wave) * 8 + sr;                                   \
            gl_lds16(B + (size_t)(n0 + rr) * K + (k0) + ss * 8,                 \
                     &Bs[buf][(c * 4 + wave) * 512]);                           \
        }                                                                       \
    }

    GEMM_STAGE(0, 0)

    for (int t = 0; t < NT; t++) {
        __syncthreads();                       // drains DMA for tile t
        if (t + 1 < NT) GEMM_STAGE((t + 1) & 1, (t + 1) << 6)
        const unsigned short* ab = As[t & 1];
        const unsigned short* bb = Bs[t & 1];
        __builtin_amdgcn_s_setprio(1);
#pragma unroll
        for (int ks = 0; ks < 2; ks++) {
            short8 af[4], bfr[NB];
#pragma unroll
            for (int m = 0; m < 4; m++)
                af[m] = *(const short8*)&ab[(wm + m * 16 + fr) * 64 +
                                            (((ks * 4 + fg) ^ (fr & 7)) << 3)];
#pragma unroll
            for (int n = 0; n < NB; n++)
                bfr[n] = *(const short8*)&bb[(wn + n * 16 + fr) * 64 +
                                             (((ks * 4 + fg) ^ (fr & 7)) << 3)];
#pragma unroll
            for (int m = 0; m < 4; m++)
#pragma unroll
                for (int n = 0; n < NB; n++)
                    acc[m][n] = __builtin_amdgcn_mfma_f32_16x16x32_bf16(
                        af[m], bfr[n], acc[m][n], 0, 0, 0);
        }
        __builtin_amdgcn_s_setprio(0);
    }
#undef GEMM_STAGE

#pragma unroll
    for (int m = 0; m < 4; m++) {
#pragma unroll
        for (int n = 0; n < NB; n++) {
            int gn = n0 + wn + n * 16 + fr;
            float bv = bias[gn];
#pragma unroll
            for (int j = 0; j < 4; j++) {
                int gm = m0 + wm + m * 16 + fg * 4 + j;
                float v = acc[m][n][j] + bv;
                if (EPI == 0) {
                    int which = gn / 768, rem = gn % 768;
                    int h = rem >> 6, d = rem & 63;
                    int b = gm >> 12, nn = gm & 4095;
                    if (which == 0) v *= (0.125f * LOG2E);
                    unsigned short* o = (unsigned short*)Cout;
                    size_t base = (((size_t)which * 2 + b) * 12 + h) * 262144;
                    if (which == 2)
                        o[base + (size_t)d * 4096 + nn] = f2bf(v);   // V^T plain
                    else
                        o[base + (size_t)nn * 64 + d] = f2bf(v);     // Q,K plain
                } else {
                    float* o = (float*)Cout;
                    o[(size_t)gm * 768 + gn] = v;
                }
            }
        }
    }
}

// ---------------- Flash attention (32x32, reg-staged dist-2, pk softmax) -----
// S^T = mfma32(K_perm, Q); O^T = mfma32(V^T, P); all softmax state lane-local.
__global__ __launch_bounds__(256, 3)
void attn_fwd(const unsigned short* __restrict__ qkv,
              unsigned short* __restrict__ outp) {
    __shared__ unsigned short Ks[64][72];
    __shared__ unsigned short Vt[64][72];        // plain V^T: Vt[d][k]

    const int tid  = threadIdx.x;
    const int wave = tid >> 6, lane = tid & 63;
    const int l31 = lane & 31, hh = lane >> 5;
    const int l31p = (l31 & 0x13) | ((l31 & 4) << 1) | ((l31 & 8) >> 1); // b2<->b3

    const int qt = blockIdx.x;
    const int bh = blockIdx.y;
    const int b = bh / 12, h = bh % 12;

    const size_t headsz = (size_t)4096 * 64;
    const unsigned short* qh  = qkv + ((size_t)b * 12 + h) * headsz;
    const unsigned short* kh  = qkv + ((size_t)(2 + b) * 12 + h) * headsz;
    const unsigned short* vht = qkv + ((size_t)(4 + b) * 12 + h) * headsz; // (hd,N)

    const int qw = qt * 128 + wave * 32;
    const int gq = qw + l31;

    short8 qf[4];
#pragma unroll
    for (int ks = 0; ks < 4; ks++)
        qf[ks] = *(const short8*)(qh + (size_t)gq * 64 + ks * 16 + hh * 8);

    float mrow = -1e30f;
    f32x16 accA = (f32x16)0.f, accB = (f32x16)0.f;
    f32x2 ls[8];
#pragma unroll
    for (int i = 0; i < 8; i++) ls[i] = (f32x2){0.f, 0.f};

    const int r = tid >> 3, sg = tid & 7;

    // prefetch distance 2: two register sets
    short8 rK[2][2], rV[2][2];
#pragma unroll
    for (int st = 0; st < 2; st++)
#pragma unroll
        for (int c = 0; c < 2; c++) {
            int kr = r + c * 32;
            rK[st][c] = *(const short8*)(kh + (size_t)st * 4096 + kr * 64 + sg * 8);
            rV[st][c] = *(const short8*)(vht + (size_t)kr * 4096 + st * 64 + sg * 8);
        }

    for (int kt = 0; kt < 64; kt++) {
        const int st = kt & 1;
        __syncthreads();
#pragma unroll
        for (int c = 0; c < 2; c++) {
            int kr = r + c * 32;
            *(short8*)&Ks[kr][sg * 8] = rK[st][c];
            *(short8*)&Vt[kr][sg * 8] = rV[st][c];
        }
        if (kt + 2 < 64) {
            const unsigned short* kb = kh + (size_t)(kt + 2) * 4096;
#pragma unroll
            for (int c = 0; c < 2; c++) {
                int kr = r + c * 32;
                rK[st][c] = *(const short8*)(kb + kr * 64 + sg * 8);
                rV[st][c] = *(const short8*)(vht + (size_t)kr * 4096 + (kt + 2) * 64 + sg * 8);
            }
        }
        __syncthreads();

        // S^T = K_perm x Q
        f32x16 s0 = (f32x16)0.f, s1 = (f32x16)0.f;
        __builtin_amdgcn_s_setprio(1);
#pragma unroll
        for (int ks = 0; ks < 4; ks++) {
            short8 kf0 = *(const short8*)&Ks[l31p][ks * 16 + hh * 8];
            short8 kf1 = *(const short8*)&Ks[32 + l31p][ks * 16 + hh * 8];
            s0 = __builtin_amdgcn_mfma_f32_32x32x16_bf16(kf0, qf[ks], s0, 0, 0, 0);
            s1 = __builtin_amdgcn_mfma_f32_32x32x16_bf16(kf1, qf[ks], s1, 0, 0, 0);
        }
        __builtin_amdgcn_s_setprio(0);

        union F16 { f32x16 v; f32x2 p[8]; float f[16]; };
        F16 a, b2;
        a.v = s0; b2.v = s1;

        // packed max tree (15 pk ops) + 1 shfl
        f32x2 m2[8];
#pragma unroll
        for (int i = 0; i < 8; i++) m2[i] = __builtin_elementwise_max(a.p[i], b2.p[i]);
#pragma unroll
        for (int i = 0; i < 4; i++) m2[i] = __builtin_elementwise_max(m2[i], m2[i + 4]);
        m2[0] = __builtin_elementwise_max(m2[0], m2[2]);
        m2[1] = __builtin_elementwise_max(m2[1], m2[3]);
        m2[0] = __builtin_elementwise_max(m2[0], m2[1]);
        float mx = fmaxf(m2[0][0], m2[0][1]);
        mx = fmaxf(mx, __shfl_xor(mx, 32));

        if (!__all(mx - mrow <= 8.0f)) {      // rare rescale
            float mnew = fmaxf(mrow, mx);
            float corr = fast_exp2(mrow - mnew);
            mrow = mnew;
            f32x2 c2 = {corr, corr};
#pragma unroll
            for (int i = 0; i < 16; i++) { accA[i] *= corr; accB[i] *= corr; }
#pragma unroll
            for (int i = 0; i < 8; i++) ls[i] *= c2;
        }

        f32x2 nm = {-mrow, -mrow};
#pragma unroll
        for (int i = 0; i < 8; i++) { a.p[i] += nm; b2.p[i] += nm; }
#pragma unroll
        for (int i = 0; i < 16; i++) {
            a.f[i]  = fast_exp2(a.f[i]);
            b2.f[i] = fast_exp2(b2.f[i]);
        }
#pragma unroll
        for (int i = 0; i < 8; i++) ls[i] += a.p[i] + b2.p[i];

        // pack P in-register (order matches PV B-operand slots)
        short8 pf[4];
        {
            union { unsigned w[4]; short8 v; } up;
            up.w[0] = cvt_pk_bf16(a.f[0], a.f[1]);   up.w[1] = cvt_pk_bf16(a.f[2], a.f[3]);
            up.w[2] = cvt_pk_bf16(a.f[4], a.f[5]);   up.w[3] = cvt_pk_bf16(a.f[6], a.f[7]);
            pf[0] = up.v;
            up.w[0] = cvt_pk_bf16(a.f[8], a.f[9]);   up.w[1] = cvt_pk_bf16(a.f[10], a.f[11]);
            up.w[2] = cvt_pk_bf16(a.f[12], a.f[13]); up.w[3] = cvt_pk_bf16(a.f[14], a.f[15]);
            pf[1] = up.v;
            up.w[0] = cvt_pk_bf16(b2.f[0], b2.f[1]);   up.w[1] = cvt_pk_bf16(b2.f[2], b2.f[3]);
            up.w[2] = cvt_pk_bf16(b2.f[4], b2.f[5]);   up.w[3] = cvt_pk_bf16(b2.f[6], b2.f[7]);
            pf[2] = up.v;
            up.w[0] = cvt_pk_bf16(b2.f[8], b2.f[9]);   up.w[1] = cvt_pk_bf16(b2.f[10], b2.f[11]);
            up.w[2] = cvt_pk_bf16(b2.f[12], b2.f[13]); up.w[3] = cvt_pk_bf16(b2.f[14], b2.f[15]);
            pf[3] = up.v;
        }

        // O^T += V^T x P
        __builtin_amdgcn_s_setprio(1);
#pragma unroll
        for (int ks2 = 0; ks2 < 4; ks2++) {
            short8 vf0 = *(const short8*)&Vt[l31][ks2 * 16 + hh * 8];
            short8 vf1 = *(const short8*)&Vt[32 + l31][ks2 * 16 + hh * 8];
            accA = __builtin_amdgcn_mfma_f32_32x32x16_bf16(vf0, pf[ks2], accA, 0, 0, 0);
            accB = __builtin_amdgcn_mfma_f32_32x32x16_bf16(vf1, pf[ks2], accB, 0, 0, 0);
        }
        __builtin_amdgcn_s_setprio(0);
    }

    // final l: packed tree + cross-half shfl
#pragma unroll
    for (int w = 4; w >= 1; w >>= 1)
#pragma unroll
        for (int i = 0; i < 4; i++)
            if (i < w) ls[i] += ls[i + w];
    float lr = ls[0][0] + ls[0][1];
    lr += __shfl_xor(lr, 32);
    float inv = 1.0f / lr;

    // epilogue: write att swizzled as GEMM-A operand (slot ^= row&7)
    size_t rowoff = (size_t)(b * 4096 + gq) * 768 + h * 64;
    int sw = l31 & 7;
#pragma unroll
    for (int g = 0; g < 4; g++) {
        ushort4 o;
        o.x = f2bf(accA[4 * g + 0] * inv);
        o.y = f2bf(accA[4 * g + 1] * inv);
        o.z = f2bf(accA[4 * g + 2] * inv);
        o.w = f2bf(accA[4 * g + 3] * inv);
        *(ushort4*)(outp + rowoff + ((g ^ sw) * 8) + hh * 4) = o;
        o.x = f2bf(accB[4 * g + 0] * inv);
        o.y = f2bf(accB[4 * g + 1] * inv);
        o.z = f2bf(accB[4 * g + 2] * inv);
        o.w = f2bf(accB[4 * g + 3] * inv);
        *(ushort4*)(outp + rowoff + (((4 + g) ^ sw) * 8) + hh * 4) = o;
    }
}

// ---------------- launch ----------------
extern "C" void kernel_launch(void* const* d_in, const int* in_sizes, int n_in,
                              void* d_out, int out_size, void* d_ws, size_t ws_size,
                              hipStream_t stream) {
    const float* x      = (const float*)d_in[0];
    const float* qkv_w  = (const float*)d_in[1];
    const float* qkv_b  = (const float*)d_in[2];
    const float* proj_w = (const float*)d_in[3];
    const float* proj_b = (const float*)d_in[4];
    float* out = (float*)d_out;

    char* ws = (char*)d_ws;
    unsigned short* x_bf    = (unsigned short*)(ws);              // 12,582,912 B
    unsigned short* w1_bf   = (unsigned short*)(ws + 12582912);   //  3,538,944 B
    unsigned short* w2_bf   = (unsigned short*)(ws + 16121856);   //  1,179,648 B
    unsigned short* qkv_sep = (unsigned short*)(ws + 17301504);   // 37,748,736 B
    unsigned short* att     = (unsigned short*)(ws + 55050240);   // 12,582,912 B

    cvt_swz<<<2048, 256, 0, stream>>>(x,      x_bf,  6291456 / 8);
    cvt_swz<<<864,  256, 0, stream>>>(qkv_w,  w1_bf, 1769472 / 8);
    cvt_swz<<<288,  256, 0, stream>>>(proj_w, w2_bf,  589824 / 8);

    gemm_bt<0, 128><<<dim3(18, 64), 256, 0, stream>>>(x_bf, w1_bf, qkv_b, qkv_sep,
                                                      8192, 2304, 768);

    attn_fwd<<<dim3(32, 24), 256, 0, stream>>>(qkv_sep, att);

    gemm_bt<1, 64><<<dim3(12, 64), 256, 0, stream>>>(att, w2_bf, proj_b, out,
                                                     8192, 768, 768);
}

// Round 9
// 228.255 us; speedup vs baseline: 5.1866x; 5.1866x over previous
//
#include <hip/hip_runtime.h>
#include <hip/hip_bf16.h>

#define LOG2E 1.44269504088896340736f

typedef __attribute__((ext_vector_type(8))) short short8;
typedef __attribute__((ext_vector_type(2))) float f32x2;
typedef __attribute__((ext_vector_type(4))) float f32x4;
typedef __attribute__((ext_vector_type(16))) float f32x16;

__device__ __forceinline__ unsigned short f2bf(float f) {
    unsigned int u = __float_as_uint(f);
    u += 0x7fffu + ((u >> 16) & 1u);
    return (unsigned short)(u >> 16);
}

__device__ __forceinline__ unsigned cvt_pk_bf16(float a, float b) {
    unsigned r;
    asm("v_cvt_pk_bf16_f32 %0, %1, %2" : "=v"(r) : "v"(a), "v"(b));
    return r;   // low16 = bf16(a), high16 = bf16(b)
}

__device__ __forceinline__ float fast_exp2(float x) {
    float r;
    asm("v_exp_f32 %0, %1" : "=v"(r) : "v"(x));
    return r;
}

// async global(16B/lane) -> LDS (wave-uniform base + lane*16)
__device__ __forceinline__ void gl_lds16(const unsigned short* g, unsigned short* l) {
    __builtin_amdgcn_global_load_lds(
        (const __attribute__((address_space(1))) unsigned int*)g,
        (__attribute__((address_space(3))) unsigned int*)l, 16, 0, 0);
}

// ---------------- fp32 -> bf16 conversion, XOR-swizzled (ncols = 768) -------
// within each 64-col tile: 8-u16 slot' = slot ^ (row&7)
__global__ void cvt_swz(const float* __restrict__ in,
                        unsigned short* __restrict__ out, int n8) {
    int stride = gridDim.x * blockDim.x;
    for (int i = blockIdx.x * blockDim.x + threadIdx.x; i < n8; i += stride) {
        int flat = i * 8;
        int row = flat / 768;
        int col = flat - row * 768;
        float4 v0 = ((const float4*)(in + flat))[0];
        float4 v1 = ((const float4*)(in + flat))[1];
        union { unsigned short u[8]; short8 v; } o;
        o.u[0] = f2bf(v0.x); o.u[1] = f2bf(v0.y);
        o.u[2] = f2bf(v0.z); o.u[3] = f2bf(v0.w);
        o.u[4] = f2bf(v1.x); o.u[5] = f2bf(v1.y);
        o.u[6] = f2bf(v1.z); o.u[7] = f2bf(v1.w);
        int c = (col & 63) ^ ((row & 7) << 3);
        *(short8*)(out + (size_t)row * 768 + (col & ~63) + c) = o.v;
    }
}

// ---------------- GEMM: C[m][n] = sum_k A[m][k]*B[n][k] (+bias) ----------------
// A,B pre-swizzled in HBM; LDS linear dbuf via global_load_lds; 1 barrier/iter.
// BN: 128 (4 B-frags/wave) or 64 (2 B-frags, better grid balance for small N).
// EPI==0: scatter to qkv_sep; Q pre-scaled; K (N,hd) and V^T (hd,N) PLAIN.
// EPI==1: fp32 out (M x N).
template <int EPI, int BN>
__global__ __launch_bounds__(256, BN == 64 ? 3 : 2)
void gemm_bt(const unsigned short* __restrict__ A,
             const unsigned short* __restrict__ B,
             const float* __restrict__ bias,
             void* __restrict__ Cout,
             int M, int N, int K) {
    __shared__ unsigned short As[2][8192];      // [128][64] linear per buf
    __shared__ unsigned short Bs[2][BN * 64];
    constexpr int NB = BN / 32;                 // B frags per wave; B stage iters

    const int tid  = threadIdx.x;
    const int wave = tid >> 6, lane = tid & 63;
    const int fr = lane & 15, fg = lane >> 4;
    const int wm = (wave >> 1) * 64, wn = (wave & 1) * (BN / 2);
    const int m0 = blockIdx.y * 128, n0 = blockIdx.x * BN;
    const int sr = lane >> 3, ss = lane & 7;

    f32x4 acc[4][NB];
#pragma unroll
    for (int m = 0; m < 4; m++)
#pragma unroll
        for (int n = 0; n < NB; n++) acc[m][n] = (f32x4){0.f, 0.f, 0.f, 0.f};

    const int NT = K >> 6;

    // each gl_lds16 call: 4 waves x 8 rows = 32 rows -> A: 4 iters, B: NB iters
#define GEMM_STAGE(buf, k0)                                                     \
    {                                                                           \
        _Pragma("unroll")                                                       \
        for (int c = 0; c < 4; c++) {                                           \
            int rr = (c * 4 + wave) * 8 + sr;                                   \
            gl_lds16(A + (size_t)(m0 + rr) * K + (k0) + ss * 8,                 \
                     &As[buf][(c * 4 + wave) * 512]);                           \
        }                                                                       \
        _Pragma("unroll")                                                       \
        for (int c = 0; c < NB; c++) {                                          \
            int rr = (c * 4 + wave) * 8 + sr;                                   \
            gl_lds16(B + (size_t)(n0 + rr) * K + (k0) + ss * 8,                 \
                     &Bs[buf][(c * 4 + wave) * 512]);                           \
        }                                                                       \
    }

    GEMM_STAGE(0, 0)

    for (int t = 0; t < NT; t++) {
        __syncthreads();                       // drains DMA for tile t
        if (t + 1 < NT) GEMM_STAGE((t + 1) & 1, (t + 1) << 6)
        const unsigned short* ab = As[t & 1];
        const unsigned short* bb = Bs[t & 1];
        __builtin_amdgcn_s_setprio(1);
#pragma unroll
        for (int ks = 0; ks < 2; ks++) {
            short8 af[4], bfr[NB];
#pragma unroll
            for (int m = 0; m < 4; m++)
                af[m] = *(const short8*)&ab[(wm + m * 16 + fr) * 64 +
                                            (((ks * 4 + fg) ^ (fr & 7)) << 3)];
#pragma unroll
            for (int n = 0; n < NB; n++)
                bfr[n] = *(const short8*)&bb[(wn + n * 16 + fr) * 64 +
                                             (((ks * 4 + fg) ^ (fr & 7)) << 3)];
#pragma unroll
            for (int m = 0; m < 4; m++)
#pragma unroll
                for (int n = 0; n < NB; n++)
                    acc[m][n] = __builtin_amdgcn_mfma_f32_16x16x32_bf16(
                        af[m], bfr[n], acc[m][n], 0, 0, 0);
        }
        __builtin_amdgcn_s_setprio(0);
    }
#undef GEMM_STAGE

#pragma unroll
    for (int m = 0; m < 4; m++) {
#pragma unroll
        for (int n = 0; n < NB; n++) {
            int gn = n0 + wn + n * 16 + fr;
            float bv = bias[gn];
#pragma unroll
            for (int j = 0; j < 4; j++) {
                int gm = m0 + wm + m * 16 + fg * 4 + j;
                float v = acc[m][n][j] + bv;
                if (EPI == 0) {
                    int which = gn / 768, rem = gn % 768;
                    int h = rem >> 6, d = rem & 63;
                    int b = gm >> 12, nn = gm & 4095;
                    if (which == 0) v *= (0.125f * LOG2E);
                    unsigned short* o = (unsigned short*)Cout;
                    size_t base = (((size_t)which * 2 + b) * 12 + h) * 262144;
                    if (which == 2)
                        o[base + (size_t)d * 4096 + nn] = f2bf(v);   // V^T plain
                    else
                        o[base + (size_t)nn * 64 + d] = f2bf(v);     // Q,K plain
                } else {
                    float* o = (float*)Cout;
                    o[(size_t)gm * 768 + gn] = v;
                }
            }
        }
    }
}

// ---------------- Flash attention (32x32, dist-2 NAMED reg sets, pk softmax) --
// One full K-tile iteration; rK/rV are a statically-named register set
// (no runtime indexing -> stays in VGPRs, rule #20).
__device__ __forceinline__ void attn_iter(
    short8 (&rK)[2], short8 (&rV)[2], int kt,
    const unsigned short* __restrict__ kh,
    const unsigned short* __restrict__ vht,
    int r, int sg, int l31, int l31p, int hh,
    unsigned short (&Ks)[64][72], unsigned short (&Vt)[64][72],
    const short8 (&qf)[4],
    float& mrow, f32x16& accA, f32x16& accB, f32x2 (&ls)[8]) {
    __syncthreads();
#pragma unroll
    for (int c = 0; c < 2; c++) {
        int kr = r + c * 32;
        *(short8*)&Ks[kr][sg * 8] = rK[c];
        *(short8*)&Vt[kr][sg * 8] = rV[c];
    }
    if (kt + 2 < 64) {
        const unsigned short* kb = kh + (size_t)(kt + 2) * 4096;
#pragma unroll
        for (int c = 0; c < 2; c++) {
            int kr = r + c * 32;
            rK[c] = *(const short8*)(kb + kr * 64 + sg * 8);
            rV[c] = *(const short8*)(vht + (size_t)kr * 4096 + (kt + 2) * 64 + sg * 8);
        }
    }
    __syncthreads();

    // S^T = K_perm x Q
    f32x16 s0 = (f32x16)0.f, s1 = (f32x16)0.f;
    __builtin_amdgcn_s_setprio(1);
#pragma unroll
    for (int ks = 0; ks < 4; ks++) {
        short8 kf0 = *(const short8*)&Ks[l31p][ks * 16 + hh * 8];
        short8 kf1 = *(const short8*)&Ks[32 + l31p][ks * 16 + hh * 8];
        s0 = __builtin_amdgcn_mfma_f32_32x32x16_bf16(kf0, qf[ks], s0, 0, 0, 0);
        s1 = __builtin_amdgcn_mfma_f32_32x32x16_bf16(kf1, qf[ks], s1, 0, 0, 0);
    }
    __builtin_amdgcn_s_setprio(0);

    union F16 { f32x16 v; f32x2 p[8]; float f[16]; };
    F16 a, b2;
    a.v = s0; b2.v = s1;

    // packed max tree (15 pk ops) + 1 shfl
    f32x2 m2[8];
#pragma unroll
    for (int i = 0; i < 8; i++) m2[i] = __builtin_elementwise_max(a.p[i], b2.p[i]);
#pragma unroll
    for (int i = 0; i < 4; i++) m2[i] = __builtin_elementwise_max(m2[i], m2[i + 4]);
    m2[0] = __builtin_elementwise_max(m2[0], m2[2]);
    m2[1] = __builtin_elementwise_max(m2[1], m2[3]);
    m2[0] = __builtin_elementwise_max(m2[0], m2[1]);
    float mx = fmaxf(m2[0][0], m2[0][1]);
    mx = fmaxf(mx, __shfl_xor(mx, 32));

    if (!__all(mx - mrow <= 8.0f)) {      // rare rescale
        float mnew = fmaxf(mrow, mx);
        float corr = fast_exp2(mrow - mnew);
        mrow = mnew;
        f32x2 c2 = {corr, corr};
#pragma unroll
        for (int i = 0; i < 16; i++) { accA[i] *= corr; accB[i] *= corr; }
#pragma unroll
        for (int i = 0; i < 8; i++) ls[i] *= c2;
    }

    f32x2 nm = {-mrow, -mrow};
#pragma unroll
    for (int i = 0; i < 8; i++) { a.p[i] += nm; b2.p[i] += nm; }
#pragma unroll
    for (int i = 0; i < 16; i++) {
        a.f[i]  = fast_exp2(a.f[i]);
        b2.f[i] = fast_exp2(b2.f[i]);
    }
#pragma unroll
    for (int i = 0; i < 8; i++) ls[i] += a.p[i] + b2.p[i];

    // pack P in-register (order matches PV B-operand slots)
    short8 pf[4];
    {
        union { unsigned w[4]; short8 v; } up;
        up.w[0] = cvt_pk_bf16(a.f[0], a.f[1]);   up.w[1] = cvt_pk_bf16(a.f[2], a.f[3]);
        up.w[2] = cvt_pk_bf16(a.f[4], a.f[5]);   up.w[3] = cvt_pk_bf16(a.f[6], a.f[7]);
        pf[0] = up.v;
        up.w[0] = cvt_pk_bf16(a.f[8], a.f[9]);   up.w[1] = cvt_pk_bf16(a.f[10], a.f[11]);
        up.w[2] = cvt_pk_bf16(a.f[12], a.f[13]); up.w[3] = cvt_pk_bf16(a.f[14], a.f[15]);
        pf[1] = up.v;
        up.w[0] = cvt_pk_bf16(b2.f[0], b2.f[1]);   up.w[1] = cvt_pk_bf16(b2.f[2], b2.f[3]);
        up.w[2] = cvt_pk_bf16(b2.f[4], b2.f[5]);   up.w[3] = cvt_pk_bf16(b2.f[6], b2.f[7]);
        pf[2] = up.v;
        up.w[0] = cvt_pk_bf16(b2.f[8], b2.f[9]);   up.w[1] = cvt_pk_bf16(b2.f[10], b2.f[11]);
        up.w[2] = cvt_pk_bf16(b2.f[12], b2.f[13]); up.w[3] = cvt_pk_bf16(b2.f[14], b2.f[15]);
        pf[3] = up.v;
    }

    // O^T += V^T x P
    __builtin_amdgcn_s_setprio(1);
#pragma unroll
    for (int ks2 = 0; ks2 < 4; ks2++) {
        short8 vf0 = *(const short8*)&Vt[l31][ks2 * 16 + hh * 8];
        short8 vf1 = *(const short8*)&Vt[32 + l31][ks2 * 16 + hh * 8];
        accA = __builtin_amdgcn_mfma_f32_32x32x16_bf16(vf0, pf[ks2], accA, 0, 0, 0);
        accB = __builtin_amdgcn_mfma_f32_32x32x16_bf16(vf1, pf[ks2], accB, 0, 0, 0);
    }
    __builtin_amdgcn_s_setprio(0);
}

__global__ __launch_bounds__(256, 3)
void attn_fwd(const unsigned short* __restrict__ qkv,
              unsigned short* __restrict__ outp) {
    __shared__ unsigned short Ks[64][72];
    __shared__ unsigned short Vt[64][72];        // plain V^T: Vt[d][k]

    const int tid  = threadIdx.x;
    const int wave = tid >> 6, lane = tid & 63;
    const int l31 = lane & 31, hh = lane >> 5;
    const int l31p = (l31 & 0x13) | ((l31 & 4) << 1) | ((l31 & 8) >> 1); // b2<->b3

    const int qt = blockIdx.x;
    const int bh = blockIdx.y;
    const int b = bh / 12, h = bh % 12;

    const size_t headsz = (size_t)4096 * 64;
    const unsigned short* qh  = qkv + ((size_t)b * 12 + h) * headsz;
    const unsigned short* kh  = qkv + ((size_t)(2 + b) * 12 + h) * headsz;
    const unsigned short* vht = qkv + ((size_t)(4 + b) * 12 + h) * headsz; // (hd,N)

    const int qw = qt * 128 + wave * 32;
    const int gq = qw + l31;

    short8 qf[4];
#pragma unroll
    for (int ks = 0; ks < 4; ks++)
        qf[ks] = *(const short8*)(qh + (size_t)gq * 64 + ks * 16 + hh * 8);

    float mrow = -1e30f;
    f32x16 accA = (f32x16)0.f, accB = (f32x16)0.f;
    f32x2 ls[8];
#pragma unroll
    for (int i = 0; i < 8; i++) ls[i] = (f32x2){0.f, 0.f};

    const int r = tid >> 3, sg = tid & 7;

    // prefetch distance 2: two STATICALLY NAMED register sets
    short8 rKa[2], rVa[2], rKb[2], rVb[2];
#pragma unroll
    for (int c = 0; c < 2; c++) {
        int kr = r + c * 32;
        rKa[c] = *(const short8*)(kh + (size_t)kr * 64 + sg * 8);
        rVa[c] = *(const short8*)(vht + (size_t)kr * 4096 + sg * 8);
        rKb[c] = *(const short8*)(kh + (size_t)4096 + kr * 64 + sg * 8);
        rVb[c] = *(const short8*)(vht + (size_t)kr * 4096 + 64 + sg * 8);
    }

    for (int kt = 0; kt < 64; kt += 2) {
        attn_iter(rKa, rVa, kt,     kh, vht, r, sg, l31, l31p, hh,
                  Ks, Vt, qf, mrow, accA, accB, ls);
        attn_iter(rKb, rVb, kt + 1, kh, vht, r, sg, l31, l31p, hh,
                  Ks, Vt, qf, mrow, accA, accB, ls);
    }

    // final l: packed tree + cross-half shfl
#pragma unroll
    for (int w = 4; w >= 1; w >>= 1)
#pragma unroll
        for (int i = 0; i < 4; i++)
            if (i < w) ls[i] += ls[i + w];
    float lr = ls[0][0] + ls[0][1];
    lr += __shfl_xor(lr, 32);
    float inv = 1.0f / lr;

    // epilogue: write att swizzled as GEMM-A operand (slot ^= row&7)
    size_t rowoff = (size_t)(b * 4096 + gq) * 768 + h * 64;
    int sw = l31 & 7;
#pragma unroll
    for (int g = 0; g < 4; g++) {
        ushort4 o;
        o.x = f2bf(accA[4 * g + 0] * inv);
        o.y = f2bf(accA[4 * g + 1] * inv);
        o.z = f2bf(accA[4 * g + 2] * inv);
        o.w = f2bf(accA[4 * g + 3] * inv);
        *(ushort4*)(outp + rowoff + ((g ^ sw) * 8) + hh * 4) = o;
        o.x = f2bf(accB[4 * g + 0] * inv);
        o.y = f2bf(accB[4 * g + 1] * inv);
        o.z = f2bf(accB[4 * g + 2] * inv);
        o.w = f2bf(accB[4 * g + 3] * inv);
        *(ushort4*)(outp + rowoff + (((4 + g) ^ sw) * 8) + hh * 4) = o;
    }
}

// ---------------- launch ----------------
extern "C" void kernel_launch(void* const* d_in, const int* in_sizes, int n_in,
                              void* d_out, int out_size, void* d_ws, size_t ws_size,
                              hipStream_t stream) {
    const float* x      = (const float*)d_in[0];
    const float* qkv_w  = (const float*)d_in[1];
    const float* qkv_b  = (const float*)d_in[2];
    const float* proj_w = (const float*)d_in[3];
    const float* proj_b = (const float*)d_in[4];
    float* out = (float*)d_out;

    char* ws = (char*)d_ws;
    unsigned short* x_bf    = (unsigned short*)(ws);              // 12,582,912 B
    unsigned short* w1_bf   = (unsigned short*)(ws + 12582912);   //  3,538,944 B
    unsigned short* w2_bf   = (unsigned short*)(ws + 16121856);   //  1,179,648 B
    unsigned short* qkv_sep = (unsigned short*)(ws + 17301504);   // 37,748,736 B
    unsigned short* att     = (unsigned short*)(ws + 55050240);   // 12,582,912 B

    cvt_swz<<<2048, 256, 0, stream>>>(x,      x_bf,  6291456 / 8);
    cvt_swz<<<864,  256, 0, stream>>>(qkv_w,  w1_bf, 1769472 / 8);
    cvt_swz<<<288,  256, 0, stream>>>(proj_w, w2_bf,  589824 / 8);

    gemm_bt<0, 128><<<dim3(18, 64), 256, 0, stream>>>(x_bf, w1_bf, qkv_b, qkv_sep,
                                                      8192, 2304, 768);

    attn_fwd<<<dim3(32, 24), 256, 0, stream>>>(qkv_sep, att);

    gemm_bt<1, 64><<<dim3(12, 64), 256, 0, stream>>>(att, w2_bf, proj_b, out,
                                                     8192, 768, 768);
}